// Round 14
// baseline (210.959 us; speedup 1.0000x reference)
//
#include <hip/hip_runtime.h>
#include <hip/hip_bf16.h>

#define SEQ 2048
#define DM  1024
#define NH  16
#define HDM 64

typedef __hip_bfloat16 bf16;
typedef __bf16 bhalf8 __attribute__((ext_vector_type(8)));
typedef float floatx4 __attribute__((ext_vector_type(4)));

__device__ __forceinline__ void async_cp16(const void* g, void* l) {
  __builtin_amdgcn_global_load_lds(
      (const __attribute__((address_space(1))) void*)g,
      (__attribute__((address_space(3))) void*)l, 16, 0, 0);
}

// ---- fused prep: x f32->bf16; rel f32->bf16 padded [4096][64]; W transpose
__global__ __launch_bounds__(256) void prep(
    const float* __restrict__ x, const float* __restrict__ T,
    const float* __restrict__ W0, const float* __restrict__ W1,
    const float* __restrict__ W2, const float* __restrict__ W3,
    bf16* __restrict__ xbf, bf16* __restrict__ Tbf, bf16* __restrict__ WtBase)
{
  __shared__ float tile[64][69];
  const int b = blockIdx.x;
  const int tid = threadIdx.x;
  if (b < 2048) {
    int c = b * 256 + tid;
    float4 v = *(const float4*)&x[(size_t)c * 4];
    union { bf16 h[4]; float2 f; } u;
    u.h[0] = __float2bfloat16(v.x); u.h[1] = __float2bfloat16(v.y);
    u.h[2] = __float2bfloat16(v.z); u.h[3] = __float2bfloat16(v.w);
    *(float2*)&xbf[(size_t)c * 4] = u.f;
  } else if (b < 2304) {
    int ct = (b - 2048) * 256 + tid;       // [0, 65536)
    union { bf16 h[4]; float2 f; } u;
#pragma unroll
    for (int e = 0; e < 4; ++e) {
      int se = ct * 4 + e;
      if (se >= 4095 * 64) se -= 64;       // pad row 4095 = dup of 4094
      u.h[e] = __float2bfloat16(T[se]);
    }
    *(float2*)&Tbf[(size_t)ct * 4] = u.f;
  } else {
    int tb = b - 2304;                     // [0, 1024)
    int z = tb >> 8, rem = tb & 255;
    const float* W = (z == 0) ? W0 : (z == 1) ? W1 : (z == 2) ? W2 : W3;
    bf16* Wt = WtBase + (size_t)z * DM * DM;
    const int kb = (rem >> 4) * 64, nb = (rem & 15) * 64;
    const int r = tid >> 4, c4 = (tid & 15) * 4;
#pragma unroll
    for (int rr = 0; rr < 4; ++rr) {
      float4 v = *(const float4*)&W[(size_t)(kb + rr * 16 + r) * DM + nb + c4];
      tile[rr * 16 + r][c4 + 0] = v.x; tile[rr * 16 + r][c4 + 1] = v.y;
      tile[rr * 16 + r][c4 + 2] = v.z; tile[rr * 16 + r][c4 + 3] = v.w;
    }
    __syncthreads();
    const int w = tid >> 6, l = tid & 63;
#pragma unroll
    for (int i = 0; i < 16; ++i) {
      int n = nb + w * 16 + i;
      Wt[(size_t)n * DM + kb + l] = __float2bfloat16(tile[l][w * 16 + i]);
    }
  }
}

// ---- Fused QKV projection: one GEMM [2048, 3072] = xbf @ wt^T, 128x128
// m97-style tiles, BK=32. wt rows are z*1024+n so B row index == output col.
// Per-block z is uniform (128 divides 1024). z==1 (K) scaled 1/8 (bf16-exact).
__global__ __launch_bounds__(256) void gemm_qkv(
    const bf16* __restrict__ A, const bf16* __restrict__ Bt,
    const float* __restrict__ bq, const float* __restrict__ bk,
    const float* __restrict__ bv, bf16* __restrict__ outbase)
{
  __shared__ __align__(16) bf16 As[128 * 32];
  __shared__ __align__(16) bf16 Bs[128 * 32];
  const int bm = blockIdx.y * 128, bn = blockIdx.x * 128;   // bn in [0,3072)
  const int tid = threadIdx.x;
  const int lane = tid & 63;
  const int w = tid >> 6;
  const int wx = w & 1, wy = w >> 1;
  const int ln15 = lane & 15, quad = lane >> 4;

  floatx4 acc[4][4];
#pragma unroll
  for (int i = 0; i < 4; ++i)
#pragma unroll
    for (int j = 0; j < 4; ++j) acc[i][j] = (floatx4){0.f, 0.f, 0.f, 0.f};

  for (int k0 = 0; k0 < DM; k0 += 32) {
#pragma unroll
    for (int t = 0; t < 2; ++t) {
      int cbase = w * 128 + t * 64;        // wave-uniform chunk base
      int c = cbase + lane;                // 16B chunk id, 512 total
      int row = c >> 2, col = (c & 3) * 8;
      async_cp16(A  + (size_t)(bm + row) * DM + k0 + col, As + cbase * 8);
      async_cp16(Bt + (size_t)(bn + row) * DM + k0 + col, Bs + cbase * 8);
    }
    __syncthreads();
    bhalf8 af[4], bfr[4];
#pragma unroll
    for (int i = 0; i < 4; ++i)
      af[i] = *(bhalf8*)&As[(wy * 64 + i * 16 + ln15) * 32 + quad * 8];
#pragma unroll
    for (int j = 0; j < 4; ++j)
      bfr[j] = *(bhalf8*)&Bs[(wx * 64 + j * 16 + ln15) * 32 + quad * 8];
#pragma unroll
    for (int i = 0; i < 4; ++i)
#pragma unroll
      for (int j = 0; j < 4; ++j)
        acc[i][j] = __builtin_amdgcn_mfma_f32_16x16x32_bf16(af[i], bfr[j], acc[i][j], 0, 0, 0);
    __syncthreads();
  }

  const int zc = bn >> 10;                              // uniform per block
  const float* bias = (zc == 0) ? bq : (zc == 1) ? bk : bv;
  const float kscale = (zc == 1) ? 0.125f : 1.0f;
  bf16* C = outbase + (size_t)zc * SEQ * DM;
#pragma unroll
  for (int i = 0; i < 4; ++i)
#pragma unroll
    for (int j = 0; j < 4; ++j) {
      int col = bn + wx * 64 + j * 16 + ln15;
      int c1 = col & 1023;
      float bv_ = bias[c1];
#pragma unroll
      for (int r = 0; r < 4; ++r) {
        int row = bm + wy * 64 + i * 16 + quad * 4 + r;
        float v = (acc[i][j][r] + bv_) * kscale;
        if (zc < 2)
          C[((size_t)(c1 >> 6) * SEQ + row) * HDM + (c1 & 63)] = __float2bfloat16(v);
        else
          C[(size_t)c1 * SEQ + row] = __float2bfloat16(v);
      }
    }
}

// ---- output projection with FUSED key-split merge: A-tile is merged on the
// fly from the two locally-normalized partials (w = l / (l0+l1), f32 math).
// Each A-staging thread owns one row (tid>>2); each BK=64 iter spans exactly
// one head (h = k0>>6) -> per-iter scalar l0/l1 loads. B-path stays DMA.
__global__ __launch_bounds__(256) void gemm_out(
    const bf16* __restrict__ O0, const bf16* __restrict__ O1,
    const float* __restrict__ lws, const bf16* __restrict__ Bt,
    const float* __restrict__ bias, float* __restrict__ C)
{
  __shared__ __align__(16) bf16 As[64 * 64];   // two panels [64][32]
  __shared__ __align__(16) bf16 Bs[64 * 64];
  const int bm = blockIdx.y * 64, bn = blockIdx.x * 64;
  const int tid = threadIdx.x;
  const int lane = tid & 63;
  const int w = tid >> 6;
  const int ln15 = lane & 15, quad = lane >> 4;
  const int rowt = tid >> 2, ck = (tid & 3) * 8;   // A staging: one row/thread

  floatx4 acc[4];
#pragma unroll
  for (int j = 0; j < 4; ++j) acc[j] = (floatx4){0.f, 0.f, 0.f, 0.f};

  for (int k0 = 0; k0 < DM; k0 += 64) {
    const int h = k0 >> 6;
    const float l0 = lws[(size_t)h * SEQ + bm + rowt];
    const float l1 = lws[(size_t)NH * SEQ + (size_t)h * SEQ + bm + rowt];
    const float winv = 1.f / (l0 + l1);
    const float w0 = l0 * winv, w1 = l1 * winv;
#pragma unroll
    for (int p = 0; p < 2; ++p) {
      union { bf16 hh[8]; float4 v; } u0, u1, um;
      u0.v = *(const float4*)&O0[(size_t)(bm + rowt) * DM + k0 + p * 32 + ck];
      u1.v = *(const float4*)&O1[(size_t)(bm + rowt) * DM + k0 + p * 32 + ck];
#pragma unroll
      for (int e = 0; e < 8; ++e)
        um.hh[e] = __float2bfloat16(w0 * __bfloat162float(u0.hh[e]) +
                                    w1 * __bfloat162float(u1.hh[e]));
      *(float4*)&As[p * 2048 + tid * 8] = um.v;
    }
    {
      int c = tid;                         // B chunk id
      int row = c >> 2, col = (c & 3) * 8;
      async_cp16(Bt + (size_t)(bn + row) * DM + k0 + col,      Bs + tid * 8);
      async_cp16(Bt + (size_t)(bn + row) * DM + k0 + 32 + col, Bs + 2048 + tid * 8);
    }
    __syncthreads();
#pragma unroll
    for (int kk = 0; kk < 2; ++kk) {
      bhalf8 af = *(bhalf8*)&As[kk * 2048 + (w * 16 + ln15) * 32 + quad * 8];
      bhalf8 bfr[4];
#pragma unroll
      for (int j = 0; j < 4; ++j)
        bfr[j] = *(bhalf8*)&Bs[kk * 2048 + (j * 16 + ln15) * 32 + quad * 8];
#pragma unroll
      for (int j = 0; j < 4; ++j)
        acc[j] = __builtin_amdgcn_mfma_f32_16x16x32_bf16(af, bfr[j], acc[j], 0, 0, 0);
    }
    __syncthreads();
  }

#pragma unroll
  for (int j = 0; j < 4; ++j) {
    int col = bn + j * 16 + ln15;
    float bv_ = bias[col];
#pragma unroll
    for (int r = 0; r < 4; ++r) {
      int row = bm + w * 16 + quad * 4 + r;
      C[(size_t)row * DM + col] = acc[j][r] + bv_;
    }
  }
}

// ---- Flash attention, key-split x2, band carry, shift-free softmax,
// double-buffered DMA staging, one barrier per iteration (R13 structure).
__global__ __launch_bounds__(256, 2) void attn_flash(
    const bf16* __restrict__ Q, const bf16* __restrict__ K,
    const bf16* __restrict__ Vt, const bf16* __restrict__ Tb,
    bf16* __restrict__ Opart, float* __restrict__ lws)
{
  const int i0   = blockIdx.x * 64;
  const int h    = blockIdx.y;
  const int z    = blockIdx.z;
  const int tid  = threadIdx.x;
  const int lane = tid & 63;
  const int wrow = (tid >> 6) * 16;
  const int ln15 = lane & 15;
  const int quad = lane >> 4;

  // [0,16384) K bufs | [16384,32768) V bufs | [32768,49152) T bufs
  // [49152,58368) Ps | [58368,75264) S2c f32 [64][66] (Qs overlaps, pre-loop)
  __shared__ __align__(16) unsigned char smem[75264];
  bf16*  Ps  = (bf16*)(smem + 49152);       // [64][72]
  float* S2c = (float*)(smem + 58368);      // [64][66] f32
  bf16*  Qs  = (bf16*)(smem + 58368);       // [64][72]

  const bf16* Qg = Q  + ((size_t)h * SEQ + i0) * HDM;
  const bf16* Kg = K  + (size_t)h * SEQ * HDM;
  const bf16* Vg = Vt + (size_t)h * HDM * SEQ;

  const int r4 = tid >> 2, c8 = (tid & 3) * 8;   // staging chunk coords
  auto stage = [&](int jt_, int b) {
    int j0_ = jt_ * 64;
    int rb_ = i0 - j0_ + SEQ - HDM;
    bf16* Kd = (bf16*)smem + b * 4096;
    bf16* Vd = (bf16*)smem + 8192 + b * 4096;
    bf16* Td = (bf16*)smem + 16384 + b * 4096;
    async_cp16(Kg + (size_t)(j0_ + r4) * HDM + c8,        Kd + tid * 8);
    async_cp16(Kg + (size_t)(j0_ + r4) * HDM + 32 + c8,   Kd + 2048 + tid * 8);
    async_cp16(Vg + (size_t)r4 * SEQ + j0_ + c8,          Vd + tid * 8);
    async_cp16(Vg + (size_t)r4 * SEQ + j0_ + 32 + c8,     Vd + 2048 + tid * 8);
    async_cp16(Tb + (size_t)(rb_ + r4) * HDM + c8,        Td + tid * 8);
    async_cp16(Tb + (size_t)(rb_ + r4) * HDM + 32 + c8,   Td + 2048 + tid * 8);
  };

  const int jt0 = z * 16;
  stage(jt0, 0);   // prefetch first tile; lands during Q/carry preamble

#pragma unroll
  for (int t = 0; t < 2; ++t) {
    int id = tid + t * 256;
    int r = id >> 3, c = (id & 7) * 8;
    *(float4*)&Qs[r * 72 + c] = *(const float4*)&Qg[(size_t)r * HDM + c];
  }
  __syncthreads();

  const bhalf8 aq0 = *(bhalf8*)&Qs[(wrow + ln15) * 72 + quad * 8];
  const bhalf8 aq1 = *(bhalf8*)&Qs[(wrow + ln15) * 72 + quad * 8 + 32];

  floatx4 o[4];
  float lsum[4];
#pragma unroll
  for (int c = 0; c < 4; ++c) { o[c] = (floatx4){0.f, 0.f, 0.f, 0.f}; lsum[c] = 0.f; }

  const int rb0 = i0 - jt0 * 64 + SEQ - HDM;
  floatx4 carry[4];
#pragma unroll
  for (int ct = 0; ct < 4; ++ct) {
    const bf16* tr = Tb + (size_t)(rb0 + 64 + ct * 16 + ln15) * HDM + quad * 8;
    bhalf8 b0 = *(const bhalf8*)tr;
    bhalf8 b1 = *(const bhalf8*)(tr + 32);
    floatx4 a = (floatx4){0.f, 0.f, 0.f, 0.f};
    a = __builtin_amdgcn_mfma_f32_16x16x32_bf16(aq0, b0, a, 0, 0, 0);
    a = __builtin_amdgcn_mfma_f32_16x16x32_bf16(aq1, b1, a, 0, 0, 0);
    carry[ct] = a;
  }

  int cur = 0;
  for (int jt = jt0; jt < jt0 + 16; ++jt) {
    __syncthreads();   // drains vmcnt: buf[cur] DMA complete; prev readers done
    if (jt + 1 < jt0 + 16) stage(jt + 1, cur ^ 1);   // overlap with compute
    const bf16* Ksc = (bf16*)smem + cur * 4096;
    const bf16* Vsc = (bf16*)smem + 8192 + cur * 4096;
    const bf16* Tsc = (bf16*)smem + 16384 + cur * 4096;

    floatx4 fresh[4];
#pragma unroll
    for (int ct = 0; ct < 4; ++ct) {
      bhalf8 b0 = *(bhalf8*)&Tsc[(ct * 16 + ln15) * 32 + quad * 8];
      bhalf8 b1 = *(bhalf8*)&Tsc[2048 + (ct * 16 + ln15) * 32 + quad * 8];
      floatx4 a = (floatx4){0.f, 0.f, 0.f, 0.f};
      a = __builtin_amdgcn_mfma_f32_16x16x32_bf16(aq0, b0, a, 0, 0, 0);
      a = __builtin_amdgcn_mfma_f32_16x16x32_bf16(aq1, b1, a, 0, 0, 0);
      fresh[ct] = a;
    }
#pragma unroll
    for (int ct = 0; ct < 4; ++ct) {
      int t = ct * 16 + ln15;
#pragma unroll
      for (int r = 0; r < 4; ++r) {
        int row = wrow + quad * 4 + r;
        if (t >= row) S2c[row * 66 + (row + 63 - t)] = fresh[ct][r];
        else          S2c[row * 66 + (row - 1 - t)] = carry[ct][r];
      }
      carry[ct] = fresh[ct];
    }

#pragma unroll
    for (int ct = 0; ct < 4; ++ct) {
      floatx4 s2f;
#pragma unroll
      for (int r = 0; r < 4; ++r)
        s2f[r] = S2c[(wrow + quad * 4 + r) * 66 + ct * 16 + ln15];
      bhalf8 b0 = *(bhalf8*)&Ksc[(ct * 16 + ln15) * 32 + quad * 8];
      bhalf8 b1 = *(bhalf8*)&Ksc[2048 + (ct * 16 + ln15) * 32 + quad * 8];
      floatx4 a = __builtin_amdgcn_mfma_f32_16x16x32_bf16(aq0, b0, s2f, 0, 0, 0);
      a = __builtin_amdgcn_mfma_f32_16x16x32_bf16(aq1, b1, a, 0, 0, 0);
#pragma unroll
      for (int r = 0; r < 4; ++r) {
        float p = __expf(a[r]);
        lsum[r] += p;
        Ps[(wrow + quad * 4 + r) * 72 + ct * 16 + ln15] = __float2bfloat16(p);
      }
    }

    bhalf8 ap0 = *(bhalf8*)&Ps[(wrow + ln15) * 72 + quad * 8];
    bhalf8 ap1 = *(bhalf8*)&Ps[(wrow + ln15) * 72 + quad * 8 + 32];
#pragma unroll
    for (int ct = 0; ct < 4; ++ct) {
      bhalf8 b0 = *(bhalf8*)&Vsc[(ct * 16 + ln15) * 32 + quad * 8];
      bhalf8 b1 = *(bhalf8*)&Vsc[2048 + (ct * 16 + ln15) * 32 + quad * 8];
      o[ct] = __builtin_amdgcn_mfma_f32_16x16x32_bf16(ap0, b0, o[ct], 0, 0, 0);
      o[ct] = __builtin_amdgcn_mfma_f32_16x16x32_bf16(ap1, b1, o[ct], 0, 0, 0);
    }
    cur ^= 1;
  }

  // epilogue: one shuffle-reduce of l per row; locally-normalized partial + l
  bf16* Oz = Opart + (size_t)z * SEQ * DM;
#pragma unroll
  for (int r = 0; r < 4; ++r) {
    float l = lsum[r];
    l += __shfl_xor(l, 1); l += __shfl_xor(l, 2);
    l += __shfl_xor(l, 4); l += __shfl_xor(l, 8);
    float inv = 1.f / l;
    int row = i0 + wrow + quad * 4 + r;
#pragma unroll
    for (int ct = 0; ct < 4; ++ct)
      Oz[(size_t)row * DM + h * HDM + ct * 16 + ln15] =
          __float2bfloat16(o[ct][r] * inv);
    if (ln15 == 0)
      lws[((size_t)z * NH + h) * SEQ + row] = l;
  }
}

extern "C" void kernel_launch(void* const* d_in, const int* in_sizes, int n_in,
                              void* d_out, int out_size, void* d_ws, size_t ws_size,
                              hipStream_t stream) {
  const float* x   = (const float*)d_in[0];
  const float* Wq  = (const float*)d_in[1];
  const float* bq  = (const float*)d_in[2];
  const float* Wk  = (const float*)d_in[3];
  const float* bk  = (const float*)d_in[4];
  const float* Wv  = (const float*)d_in[5];
  const float* bv  = (const float*)d_in[6];
  const float* Wo  = (const float*)d_in[7];
  const float* bo  = (const float*)d_in[8];
  const float* rel = (const float*)d_in[9];
  float* out = (float*)d_out;

  const size_t SD = (size_t)SEQ * DM;      // 2M elems
  bf16* qws = (bf16*)d_ws;                 // [H][S][64]
  bf16* kws = qws + SD;                    // [H][S][64] (pre-scaled by 1/8)
  bf16* vws = kws + SD;                    // Vt [D][S]
  bf16* xbf = vws + SD;                    // [S][D]
  bf16* wt  = xbf + SD;                    // 4 x [n][k] (q,k,v,o)
  bf16* tbf = wt + 4 * (size_t)DM * DM;    // [4096][64]
  bf16* opart = tbf + (size_t)4096 * HDM;  // 2 x [S][D] partials
  float* lws  = (float*)(opart + 2 * SD);  // [2][NH][SEQ]

  prep<<<3328, 256, 0, stream>>>(x, rel, Wq, Wk, Wv, Wo, xbf, tbf, wt);
  gemm_qkv<<<dim3(24, 16), 256, 0, stream>>>(xbf, wt, bq, bk, bv, qws);
  attn_flash<<<dim3(SEQ / 64, NH, 2), 256, 0, stream>>>(qws, kws, vws, tbf,
                                                        opart, lws);
  gemm_out<<<dim3(16, 32), 256, 0, stream>>>(opart, opart + SD, lws,
                                             wt + 3 * (size_t)DM * DM, bo, out);
}